// Round 12
// baseline (988.045 us; speedup 1.0000x reference)
//
#include <hip/hip_runtime.h>
#include <cmath>

#define DEV __device__ __forceinline__

constexpr int NA    = 32768;          // atoms
constexpr int M     = 12;             // neighbors
constexpr int ORIG  = 92;
constexpr int NBR   = 41;
constexpr int AF    = 64;
constexpr int C2    = 128;            // 2*AF
constexpr int HF    = 128;
constexpr int NCONV = 3;
constexpr int NM    = NA * M;         // 393216
constexpr int BB    = 1024;           // crystals
constexpr int TA    = 4;              // atoms per tile
constexpr int RT    = TA * M;         // 48 rows per tile
constexpr int NTILES = NA / TA;       // 8192
constexpr int GRID_CONV = 1024;       // full-width tile jobs (8 tiles each)
constexpr int GRID_APPLY = 1024;      // 32 atoms per block, exact cover
constexpr int WLD   = 132;            // W2 full-width row stride (128 + pad)
constexpr int ALD   = 44;             // A tile row stride (16B-aligned rows)

DEV float fsig(float x) { return __builtin_amdgcn_rcpf(1.f + __expf(-x)); }
DEV float fsp (float x) { return fmaxf(x, 0.f) + __logf(1.f + __expf(-fabsf(x))); }

DEV void fma4(float4& a, float s, const float4 w) {
    a.x = fmaf(s, w.x, a.x); a.y = fmaf(s, w.y, a.y);
    a.z = fmaf(s, w.z, a.z); a.w = fmaf(s, w.w, a.w);
}
DEV void fma2(float2& a, float s, const float2 w) {
    a.x = fmaf(s, w.x, a.x); a.y = fmaf(s, w.y, a.y);
}
DEV float comp4(const float4 v, int i) { return i == 0 ? v.x : i == 1 ? v.y : i == 2 ? v.z : v.w; }
DEV void add2(float2& a, const float2 b) { a.x += b.x; a.y += b.y; }
DEV void sqa2(float2& a, const float2 b) { a.x = fmaf(b.x, b.x, a.x); a.y = fmaf(b.y, b.y, a.y); }
DEV float2 shxor2(const float2 v, int m) {
    float2 r; r.x = __shfl_xor(v.x, m, 64); r.y = __shfl_xor(v.y, m, 64); return r;
}
DEV float4 shxor4(const float4 v, int m) {
    float4 r;
    r.x = __shfl_xor(v.x, m, 64); r.y = __shfl_xor(v.y, m, 64);
    r.z = __shfl_xor(v.z, m, 64); r.w = __shfl_xor(v.w, m, 64);
    return r;
}
DEV void add4(float4& a, const float4 b) { a.x += b.x; a.y += b.y; a.z += b.z; a.w += b.w; }
DEV unsigned bf16pair(float a, float b) {   // RNE pack: low=a, high=b
    unsigned ua = __float_as_uint(a), ub = __float_as_uint(b);
    ua += 0x7fffu + ((ua >> 16) & 1u);
    ub += 0x7fffu + ((ub >> 16) & 1u);
    return (ua >> 16) | (ub & 0xffff0000u);
}
DEV float2 up2(unsigned u) {                // unpack 2 bf16 -> float2
    float2 r;
    r.x = __uint_as_float(u << 16);
    r.y = __uint_as_float(u & 0xffff0000u);
    return r;
}

// ---- spx: x-update (embed for layer0, softplus(x+bn2(summed)) otherwise)
//      fused with S = x@W[0:64]+b (fp32) and P = x@W[64:128] (packed bf16) ----
template<bool FIRST>
__global__ __launch_bounds__(256, 4)
void spx_kernel(const float* __restrict__ xin,
                const float* __restrict__ summed,
                const float* __restrict__ ss2,
                const float* __restrict__ atom_fea,
                const float* __restrict__ embW,
                const float* __restrict__ embb,
                const float* __restrict__ W,
                const float* __restrict__ bias,
                float* __restrict__ xout,
                float* __restrict__ S,
                unsigned* __restrict__ Pb)
{
    __shared__ float xs[16][AF];
    __shared__ float af[FIRST ? 16 * ORIG : 4];

    const int a0 = blockIdx.x * 16, tid = threadIdx.x;

    if (FIRST) {
        for (int i = tid; i < 16 * ORIG; i += 256) af[i] = atom_fea[(size_t)a0 * ORIG + i];
        __syncthreads();
        const int row = tid >> 4, c4 = (tid & 15) * 4;
        float4 acc = *(const float4*)(embb + c4);
        #pragma unroll 4
        for (int k = 0; k < ORIG; ++k)
            fma4(acc, af[row * ORIG + k], *(const float4*)(embW + k * AF + c4));
        *(float4*)&xs[row][c4] = acc;
        *(float4*)(xout + (size_t)(a0 + row) * AF + c4) = acc;
    } else {
        const int row = tid >> 4, c4 = (tid & 15) * 4;
        const size_t o = (size_t)(a0 + row) * AF + c4;
        const float4 xi = *(const float4*)(xin + o);
        const float4 sm = *(const float4*)(summed + o);
        const float4 sc = *(const float4*)(ss2 + c4);
        const float4 sh = *(const float4*)(ss2 + AF + c4);
        float4 ov;
        ov.x = fsp(xi.x + fmaf(sm.x, sc.x, sh.x));
        ov.y = fsp(xi.y + fmaf(sm.y, sc.y, sh.y));
        ov.z = fsp(xi.z + fmaf(sm.z, sc.z, sh.z));
        ov.w = fsp(xi.w + fmaf(sm.w, sc.w, sh.w));
        *(float4*)&xs[row][c4] = ov;
        *(float4*)(xout + o) = ov;
    }
    __syncthreads();

    const int cid = tid & 31, rid = tid >> 5;
    const int c0 = cid * 8, r0 = rid * 2;
    const bool isS = (c0 < 128);
    const int cc = c0 & 127;
    const float* Wb = W + (isS ? 0 : AF * C2) + cc;
    float4 a00, a01, a10, a11;
    if (isS) { a00 = *(const float4*)(bias + cc); a01 = *(const float4*)(bias + cc + 4); }
    else     { a00 = {0,0,0,0}; a01 = {0,0,0,0}; }
    a10 = a00; a11 = a01;
    for (int k = 0; k < AF; ++k) {
        const float4 w0 = *(const float4*)(Wb + k * C2);
        const float4 w1 = *(const float4*)(Wb + k * C2 + 4);
        const float x0 = xs[r0][k], x1 = xs[r0 + 1][k];
        fma4(a00, x0, w0); fma4(a01, x0, w1);
        fma4(a10, x1, w0); fma4(a11, x1, w1);
    }
    if (isS) {
        *(float4*)(S + (size_t)(a0 + r0) * C2 + cc)     = a00;
        *(float4*)(S + (size_t)(a0 + r0) * C2 + cc + 4) = a01;
        *(float4*)(S + (size_t)(a0 + r0 + 1) * C2 + cc)     = a10;
        *(float4*)(S + (size_t)(a0 + r0 + 1) * C2 + cc + 4) = a11;
    } else {
        uint4 u0, u1;
        u0.x = bf16pair(a00.x, a00.y); u0.y = bf16pair(a00.z, a00.w);
        u0.z = bf16pair(a01.x, a01.y); u0.w = bf16pair(a01.z, a01.w);
        u1.x = bf16pair(a10.x, a10.y); u1.y = bf16pair(a10.z, a10.w);
        u1.z = bf16pair(a11.x, a11.y); u1.w = bf16pair(a11.z, a11.w);
        *(uint4*)(Pb + (size_t)(a0 + r0) * 64 + cc / 2)     = u0;
        *(uint4*)(Pb + (size_t)(a0 + r0 + 1) * 64 + cc / 2) = u1;
    }
}

// ------- conv stats pass, FULL-WIDTH, 8 tiles/block, DOUBLE-BUFFERED sA (R11):
//   R9/R10 had 2 barriers/tile with a serial staging window between them
//   (47% stall at 53% VALUBusy). Now: write tile it+1's A into the idle LDS
//   buffer CONCURRENT with the GEMM on tile it; ONE barrier per tile.
//   st[] prefetch distance = one full GEMM (~2300cyc >> 900cyc HBM latency).
//   LDS 21.6 + 2x8.45 = 38.5 KB -> still exactly 4 blocks/CU (grid 1024).
__global__ __launch_bounds__(256, 4)
void conv8_kernel(const float* __restrict__ nbr_fea,
                  const int* __restrict__ idx,
                  const float* __restrict__ W2,
                  const float* __restrict__ S,
                  const unsigned* __restrict__ Pb,
                  float* __restrict__ P1s, float* __restrict__ P1q,
                  unsigned* __restrict__ gout)
{
    __shared__ float W2h[NBR * WLD];      // 21.6 KB (full width)
    __shared__ float sA2[2][RT * ALD];    // 2 x 8.45 KB (double buffer)

    const int tid  = threadIdx.x;
    const int cid  = tid & 31;           // col pair (2 filter + 2 core)
    const int rid  = tid >> 5;           // 8 row groups x 6 edges
    const int c2   = cid * 2;
    const int r0   = rid * 6;            // first edge row of this thread
    const int atom = rid >> 1;           // 6|12 -> all 6 edges share one atom

    const int q0 = blockIdx.x;

    int j[6];
    float2 svf, svc;
    float st[8];

    // ---- prologue: tile 0 regs (issued FIRST, latency overlaps W2h staging) ----
    {
        const int n0 = q0 * TA;
        const int ib = n0 * M + r0;
        #pragma unroll
        for (int e = 0; e < 6; ++e) j[e] = idx[ib + e];
        svf = *(const float2*)(S + (size_t)(n0 + atom) * C2 + c2);
        svc = *(const float2*)(S + (size_t)(n0 + atom) * C2 + 64 + c2);
        const float* src = nbr_fea + (size_t)n0 * M * NBR;
        #pragma unroll
        for (int i = 0; i < 8; ++i)
            if (i < 7 || tid + 256 * i < RT * NBR) st[i] = src[tid + 256 * i];
    }

    // stage W2h full width (contiguous copy)
    for (int i = tid; i < NBR * 32; i += 256) {
        const int k = i >> 5, q = i & 31;
        *(float4*)&W2h[k * WLD + q * 4] = *(const float4*)(W2 + k * C2 + q * 4);
    }

    // write tile 0 into sA2[0]; then prefetch tile 1's st
    #pragma unroll
    for (int i = 0; i < 8; ++i) {
        const int e = tid + 256 * i;
        if (i < 7 || e < RT * NBR) {
            const int r = (int)(((unsigned)e * 102301u) >> 22);   // e/41
            sA2[0][r * ALD + (e - r * NBR)] = st[i];
        }
    }
    {
        const int nn0 = (q0 + GRID_CONV) * TA;
        const float* src = nbr_fea + (size_t)nn0 * M * NBR;
        #pragma unroll
        for (int i = 0; i < 8; ++i)
            if (i < 7 || tid + 256 * i < RT * NBR) st[i] = src[tid + 256 * i];
    }

    float2 sum_f = {0,0}, sum_c = {0,0}, sq_f = {0,0}, sq_c = {0,0};

    __syncthreads();                     // W2h + sA2[0] ready

    #pragma unroll 2
    for (int it = 0; it < 8; ++it) {
        const int cur = it & 1;
        const int t   = q0 + it * GRID_CONV;
        const int n0  = t * TA;

        // ---- write NEXT tile (data in st) into the idle buffer: overlaps GEMM.
        //      sA2[cur^1] reads finished at the barrier ending iter it-1. ----
        if (it < 7) {
            #pragma unroll
            for (int i = 0; i < 8; ++i) {
                const int e = tid + 256 * i;
                if (i < 7 || e < RT * NBR) {
                    const int r = (int)(((unsigned)e * 102301u) >> 22);
                    sA2[cur ^ 1][r * ALD + (e - r * NBR)] = st[i];
                }
            }
        }

        // ---- gathers for this tile (j/sv current), consumed after the GEMM ----
        unsigned uf[6], uc[6];
        #pragma unroll
        for (int e = 0; e < 6; ++e) {
            uf[e] = Pb[(size_t)j[e] * 64 + cid];
            uc[e] = Pb[(size_t)j[e] * 64 + 32 + cid];
        }
        const float2 cf = svf, cc = svc;

        // ---- prefetch j/S for tile it+1 ----
        if (it < 7) {
            const int nn0 = (t + GRID_CONV) * TA;
            const int ib = nn0 * M + r0;
            #pragma unroll
            for (int e = 0; e < 6; ++e) j[e] = idx[ib + e];
            svf = *(const float2*)(S + (size_t)(nn0 + atom) * C2 + c2);
            svc = *(const float2*)(S + (size_t)(nn0 + atom) * C2 + 64 + c2);
        }
        // ---- prefetch st for tile it+2 (consumed at iter it+1's LDS write) ----
        if (it < 6) {
            const int nn0 = (t + 2 * GRID_CONV) * TA;
            const float* src = nbr_fea + (size_t)nn0 * M * NBR;
            #pragma unroll
            for (int i = 0; i < 8; ++i)
                if (i < 7 || tid + 256 * i < RT * NBR) st[i] = src[tid + 256 * i];
        }

        // ---- E-GEMM: zero-init, += nbr @ W2h, 6 rows x (2+2) cols ----
        float2 ef0 = {0,0}, ef1 = {0,0}, ef2 = {0,0}, ef3 = {0,0}, ef4 = {0,0}, ef5 = {0,0};
        float2 ec0 = {0,0}, ec1 = {0,0}, ec2 = {0,0}, ec3 = {0,0}, ec4 = {0,0}, ec5 = {0,0};
        const float* Ab = &sA2[cur][0] + r0 * ALD;
        #pragma unroll 2
        for (int k4 = 0; k4 < 10; ++k4) {
            const float4 a0 = *(const float4*)(Ab + 0 * ALD + k4 * 4);
            const float4 a1 = *(const float4*)(Ab + 1 * ALD + k4 * 4);
            const float4 a2 = *(const float4*)(Ab + 2 * ALD + k4 * 4);
            const float4 a3 = *(const float4*)(Ab + 3 * ALD + k4 * 4);
            const float4 a4 = *(const float4*)(Ab + 4 * ALD + k4 * 4);
            const float4 a5 = *(const float4*)(Ab + 5 * ALD + k4 * 4);
            #pragma unroll
            for (int kk = 0; kk < 4; ++kk) {
                const int k = 4 * k4 + kk;
                const float2 wf = *(const float2*)(W2h + k * WLD + c2);
                const float2 wc = *(const float2*)(W2h + k * WLD + 64 + c2);
                fma2(ef0, comp4(a0, kk), wf); fma2(ec0, comp4(a0, kk), wc);
                fma2(ef1, comp4(a1, kk), wf); fma2(ec1, comp4(a1, kk), wc);
                fma2(ef2, comp4(a2, kk), wf); fma2(ec2, comp4(a2, kk), wc);
                fma2(ef3, comp4(a3, kk), wf); fma2(ec3, comp4(a3, kk), wc);
                fma2(ef4, comp4(a4, kk), wf); fma2(ec4, comp4(a4, kk), wc);
                fma2(ef5, comp4(a5, kk), wf); fma2(ec5, comp4(a5, kk), wc);
            }
        }
        {   // k = 40
            const float2 wf = *(const float2*)(W2h + 40 * WLD + c2);
            const float2 wc = *(const float2*)(W2h + 40 * WLD + 64 + c2);
            const float b0 = Ab[0 * ALD + 40], b1 = Ab[1 * ALD + 40], b2 = Ab[2 * ALD + 40];
            const float b3 = Ab[3 * ALD + 40], b4 = Ab[4 * ALD + 40], b5 = Ab[5 * ALD + 40];
            fma2(ef0, b0, wf); fma2(ec0, b0, wc);
            fma2(ef1, b1, wf); fma2(ec1, b1, wc);
            fma2(ef2, b2, wf); fma2(ec2, b2, wc);
            fma2(ef3, b3, wf); fma2(ec3, b3, wc);
            fma2(ef4, b4, wf); fma2(ec4, b4, wc);
            fma2(ef5, b5, wf); fma2(ec5, b5, wc);
        }

        // ---- fold S + P[idx], write g (bf16 pairs), BN1 stats ----
        const size_t row0 = (size_t)(n0 * M + r0) * 64 + cid;
        {
            add2(ef0, cf); add2(ef0, up2(uf[0])); add2(ec0, cc); add2(ec0, up2(uc[0]));
            add2(ef1, cf); add2(ef1, up2(uf[1])); add2(ec1, cc); add2(ec1, up2(uc[1]));
            add2(ef2, cf); add2(ef2, up2(uf[2])); add2(ec2, cc); add2(ec2, up2(uc[2]));
            add2(ef3, cf); add2(ef3, up2(uf[3])); add2(ec3, cc); add2(ec3, up2(uc[3]));
            add2(ef4, cf); add2(ef4, up2(uf[4])); add2(ec4, cc); add2(ec4, up2(uc[4]));
            add2(ef5, cf); add2(ef5, up2(uf[5])); add2(ec5, cc); add2(ec5, up2(uc[5]));
            gout[row0 + 0 * 64]      = bf16pair(ef0.x, ef0.y);
            gout[row0 + 0 * 64 + 32] = bf16pair(ec0.x, ec0.y);
            gout[row0 + 1 * 64]      = bf16pair(ef1.x, ef1.y);
            gout[row0 + 1 * 64 + 32] = bf16pair(ec1.x, ec1.y);
            gout[row0 + 2 * 64]      = bf16pair(ef2.x, ef2.y);
            gout[row0 + 2 * 64 + 32] = bf16pair(ec2.x, ec2.y);
            gout[row0 + 3 * 64]      = bf16pair(ef3.x, ef3.y);
            gout[row0 + 3 * 64 + 32] = bf16pair(ec3.x, ec3.y);
            gout[row0 + 4 * 64]      = bf16pair(ef4.x, ef4.y);
            gout[row0 + 4 * 64 + 32] = bf16pair(ec4.x, ec4.y);
            gout[row0 + 5 * 64]      = bf16pair(ef5.x, ef5.y);
            gout[row0 + 5 * 64 + 32] = bf16pair(ec5.x, ec5.y);
            add2(sum_f, ef0); add2(sum_f, ef1); add2(sum_f, ef2);
            add2(sum_f, ef3); add2(sum_f, ef4); add2(sum_f, ef5);
            add2(sum_c, ec0); add2(sum_c, ec1); add2(sum_c, ec2);
            add2(sum_c, ec3); add2(sum_c, ec4); add2(sum_c, ec5);
            sqa2(sq_f, ef0); sqa2(sq_f, ef1); sqa2(sq_f, ef2);
            sqa2(sq_f, ef3); sqa2(sq_f, ef4); sqa2(sq_f, ef5);
            sqa2(sq_c, ec0); sqa2(sq_c, ec1); sqa2(sq_c, ec2);
            sqa2(sq_c, ec3); sqa2(sq_c, ec4); sqa2(sq_c, ec5);
        }

        __syncthreads();                 // sA2[cur^1] writes visible; sA2[cur] reads done
    }

    // block reduce: xor32 sums the 2 rids in each wave, then across 4 waves via LDS
    { float2 t2 = shxor2(sum_f, 32); add2(sum_f, t2); }
    { float2 t2 = shxor2(sum_c, 32); add2(sum_c, t2); }
    { float2 t2 = shxor2(sq_f, 32);  add2(sq_f, t2);  }
    { float2 t2 = shxor2(sq_c, 32);  add2(sq_c, t2);  }
    float* sA = &sA2[0][0];              // scratch (all tiles done, last barrier passed)
    const int w = tid >> 6;
    if ((tid & 32) == 0) {
        *(float2*)&sA[w * 128 + c2]            = sum_f;
        *(float2*)&sA[w * 128 + 64 + c2]       = sum_c;
        *(float2*)&sA[512 + w * 128 + c2]      = sq_f;
        *(float2*)&sA[512 + w * 128 + 64 + c2] = sq_c;
    }
    __syncthreads();
    if (tid < 128) {
        P1s[(size_t)blockIdx.x * C2 + tid] = sA[tid] + sA[128 + tid] + sA[256 + tid] + sA[384 + tid];
        P1q[(size_t)blockIdx.x * C2 + tid] = sA[512 + tid] + sA[640 + tid]
                                           + sA[768 + tid] + sA[896 + tid];
    }
}

// ---- apply pass (R10): uint4 (16B) loads, 8 threads/atom, 32 atoms/block ----
__global__ __launch_bounds__(256)
void apply_g_kernel(const unsigned* __restrict__ g,
                    const float* __restrict__ ss1,
                    float* __restrict__ summed,
                    float* __restrict__ P2s, float* __restrict__ P2q)
{
    const int tid = threadIdx.x;
    const int al  = tid >> 3;            // 32 atoms per block
    const int c   = tid & 7;             // col octet: cols 8c..8c+7
    const int c8  = 8 * c;

    const float4 scf0 = *(const float4*)(ss1 + c8);
    const float4 scf1 = *(const float4*)(ss1 + c8 + 4);
    const float4 scc0 = *(const float4*)(ss1 + 64 + c8);
    const float4 scc1 = *(const float4*)(ss1 + 64 + c8 + 4);
    const float4 shf0 = *(const float4*)(ss1 + C2 + c8);
    const float4 shf1 = *(const float4*)(ss1 + C2 + c8 + 4);
    const float4 shc0 = *(const float4*)(ss1 + C2 + 64 + c8);
    const float4 shc1 = *(const float4*)(ss1 + C2 + 64 + c8 + 4);

    const int a = blockIdx.x * 32 + al;
    const unsigned* gr = g + (size_t)a * M * 64 + 4 * c;
    float4 acc0 = {0,0,0,0}, acc1 = {0,0,0,0};
    #pragma unroll
    for (int m = 0; m < M; ++m) {
        const uint4 uf = *(const uint4*)(gr + m * 64);
        const uint4 uc = *(const uint4*)(gr + m * 64 + 32);
        const float2 f0 = up2(uf.x), f1 = up2(uf.y), f2 = up2(uf.z), f3 = up2(uf.w);
        const float2 s0 = up2(uc.x), s1 = up2(uc.y), s2 = up2(uc.z), s3 = up2(uc.w);
        acc0.x = fmaf(fsig(fmaf(f0.x, scf0.x, shf0.x)), fsp(fmaf(s0.x, scc0.x, shc0.x)), acc0.x);
        acc0.y = fmaf(fsig(fmaf(f0.y, scf0.y, shf0.y)), fsp(fmaf(s0.y, scc0.y, shc0.y)), acc0.y);
        acc0.z = fmaf(fsig(fmaf(f1.x, scf0.z, shf0.z)), fsp(fmaf(s1.x, scc0.z, shc0.z)), acc0.z);
        acc0.w = fmaf(fsig(fmaf(f1.y, scf0.w, shf0.w)), fsp(fmaf(s1.y, scc0.w, shc0.w)), acc0.w);
        acc1.x = fmaf(fsig(fmaf(f2.x, scf1.x, shf1.x)), fsp(fmaf(s2.x, scc1.x, shc1.x)), acc1.x);
        acc1.y = fmaf(fsig(fmaf(f2.y, scf1.y, shf1.y)), fsp(fmaf(s2.y, scc1.y, shc1.y)), acc1.y);
        acc1.z = fmaf(fsig(fmaf(f3.x, scf1.z, shf1.z)), fsp(fmaf(s3.x, scc1.z, shc1.z)), acc1.z);
        acc1.w = fmaf(fsig(fmaf(f3.y, scf1.w, shf1.w)), fsp(fmaf(s3.y, scc1.w, shc1.w)), acc1.w);
    }
    *(float4*)(summed + (size_t)a * AF + c8)     = acc0;
    *(float4*)(summed + (size_t)a * AF + c8 + 4) = acc1;

    // BN2 partials: squares, then wave xor-reduce over the 8 atoms in the wave
    float4 tq0, tq1;
    tq0.x = acc0.x * acc0.x; tq0.y = acc0.y * acc0.y;
    tq0.z = acc0.z * acc0.z; tq0.w = acc0.w * acc0.w;
    tq1.x = acc1.x * acc1.x; tq1.y = acc1.y * acc1.y;
    tq1.z = acc1.z * acc1.z; tq1.w = acc1.w * acc1.w;
    float4 ts0 = acc0, ts1 = acc1;
    #pragma unroll
    for (int msk = 8; msk <= 32; msk <<= 1) {
        add4(ts0, shxor4(ts0, msk));
        add4(ts1, shxor4(ts1, msk));
        add4(tq0, shxor4(tq0, msk));
        add4(tq1, shxor4(tq1, msk));
    }

    __shared__ float ws[4][8][16];       // [wave][col-octet][ts0..7, tq0..7]
    if ((tid & 63) < 8) {
        float* d = &ws[tid >> 6][c][0];
        *(float4*)(d)      = ts0;
        *(float4*)(d + 4)  = ts1;
        *(float4*)(d + 8)  = tq0;
        *(float4*)(d + 12) = tq1;
    }
    __syncthreads();
    if (tid < 64) {
        const int c_ = tid >> 3, o = tid & 7;
        const float s = ws[0][c_][o] + ws[1][c_][o] + ws[2][c_][o] + ws[3][c_][o];
        const float q = ws[0][c_][8 + o] + ws[1][c_][8 + o]
                      + ws[2][c_][8 + o] + ws[3][c_][8 + o];
        P2s[(size_t)blockIdx.x * AF + tid] = s;
        P2q[(size_t)blockIdx.x * AF + tid] = q;
    }
}

// ---- plain BN finalize (BN1 & BN2): partials [npart][C] ----
__global__ __launch_bounds__(256)
void bn_finalize_plain(const float* __restrict__ Ps, const float* __restrict__ Pq,
                       int npart, int C, float invn,
                       const float* __restrict__ gamma, const float* __restrict__ beta,
                       float* __restrict__ ss)
{
    __shared__ float sd[256];
    const int c = blockIdx.x, tid = threadIdx.x;
    float s = 0.f;
    for (int j = tid; j < npart; j += 256) s += Ps[(size_t)j * C + c];
    sd[tid] = s; __syncthreads();
    for (int st = 128; st > 0; st >>= 1) { if (tid < st) sd[tid] += sd[tid + st]; __syncthreads(); }
    const float total = sd[0];
    __syncthreads();
    float q = 0.f;
    for (int j = tid; j < npart; j += 256) q += Pq[(size_t)j * C + c];
    sd[tid] = q; __syncthreads();
    for (int st = 128; st > 0; st >>= 1) { if (tid < st) sd[tid] += sd[tid + st]; __syncthreads(); }
    if (tid == 0) {
        const float mean = total * invn;
        const float var  = sd[0] * invn - mean * mean;
        const float scl  = gamma[c] * rsqrtf(var + 1e-5f);
        ss[c]     = scl;
        ss[C + c] = beta[c] - mean * scl;
    }
}

// ---------------- head: fused x-update + pool + MLP ----------------
__global__ __launch_bounds__(128)
void head_kernel(const float* __restrict__ x,
                 const float* __restrict__ summed,
                 const float* __restrict__ ss2,
                 const float* __restrict__ fc1W, const float* __restrict__ fc1b,
                 const float* __restrict__ fc2W, const float* __restrict__ fc2b,
                 const float* __restrict__ outW, const float* __restrict__ outb,
                 float* __restrict__ out)
{
    __shared__ float l0[AF], l1[HF], rr[2], hs[2][AF];
    const int b = blockIdx.x, tid = threadIdx.x;
    const int col = tid & 63, half = tid >> 6;
    {
        const float sc = ss2[col], sh = ss2[AF + col];
        float s = 0.f;
        #pragma unroll 4
        for (int a = half * 16; a < half * 16 + 16; ++a) {
            const size_t o = (size_t)(b * 32 + a) * AF + col;
            s += fsp(x[o] + fmaf(summed[o], sc, sh));
        }
        hs[half][col] = s;
    }
    __syncthreads();
    if (tid < AF) l0[tid] = fsp((hs[0][tid] + hs[1][tid]) * (1.f / 32.f));
    __syncthreads();
    float acc = fc1b[tid];
    #pragma unroll 4
    for (int k = 0; k < AF; ++k) acc = fmaf(l0[k], fc1W[k * HF + tid], acc);
    l1[tid] = fsp(acc);
    __syncthreads();
    acc = fc2b[tid];
    #pragma unroll 4
    for (int k = 0; k < HF; ++k) acc = fmaf(l1[k], fc2W[k * HF + tid], acc);
    float v = fsp(acc) * outW[tid];
    #pragma unroll
    for (int off = 32; off > 0; off >>= 1) v += __shfl_down(v, off, 64);
    if ((tid & 63) == 0) rr[tid >> 6] = v;
    __syncthreads();
    if (tid == 0) out[b] = rr[0] + rr[1] + outb[0];
}

extern "C" void kernel_launch(void* const* d_in, const int* in_sizes, int n_in,
                              void* d_out, int out_size, void* d_ws, size_t ws_size,
                              hipStream_t stream)
{
    const float* atom_fea = (const float*)d_in[0];
    const float* nbr_fea  = (const float*)d_in[1];
    const int*   nbr_idx  = (const int*)d_in[2];
    const float* emb_W  = (const float*)d_in[4];
    const float* emb_b  = (const float*)d_in[5];
    const float* conv_W = (const float*)d_in[6];
    const float* conv_b = (const float*)d_in[7];
    const float* bn1_g  = (const float*)d_in[8];
    const float* bn1_b  = (const float*)d_in[9];
    const float* bn2_g  = (const float*)d_in[10];
    const float* bn2_b  = (const float*)d_in[11];
    const float* fc1W   = (const float*)d_in[12];
    const float* fc1b   = (const float*)d_in[13];
    const float* fc2W   = (const float*)d_in[14];
    const float* fc2b   = (const float*)d_in[15];
    const float* outW   = (const float*)d_in[16];
    const float* outb   = (const float*)d_in[17];
    float* out = (float*)d_out;
    float* ws  = (float*)d_ws;

    // workspace (~145 MB)
    float*    x_a    = ws;
    float*    x_b    = x_a + (size_t)NA * AF;
    float*    Sbuf   = x_b + (size_t)NA * AF;
    unsigned* Pb     = (unsigned*)(Sbuf + (size_t)NA * C2);   // NA x 64 uints (bf16 pairs)
    float*    summed = (float*)(Pb + (size_t)NA * 64);
    float*    P1s    = summed + (size_t)NA * AF;              // [1024][128]
    float*    P1q    = P1s + (size_t)GRID_CONV * C2;
    float*    P2s    = P1q + (size_t)GRID_CONV * C2;          // [1024][64]
    float*    P2q    = P2s + (size_t)GRID_APPLY * AF;
    float*    ss1    = P2q + (size_t)GRID_APPLY * AF;
    float*    ss2    = ss1 + 2 * C2;
    unsigned* gbuf   = (unsigned*)(ss2 + 2 * AF);             // NM x 64 uints (bf16 pairs)

    float* xcur = x_a;
    spx_kernel<true><<<NA / 16, 256, 0, stream>>>(nullptr, nullptr, nullptr,
                                                  atom_fea, emb_W, emb_b,
                                                  conv_W, conv_b, xcur, Sbuf, Pb);
    for (int l = 0; l < NCONV; ++l) {
        const float* W2 = conv_W + (size_t)l * (C2 + NBR) * C2 + (size_t)C2 * C2;
        conv8_kernel<<<GRID_CONV, 256, 0, stream>>>(nbr_fea, nbr_idx, W2,
                                                    Sbuf, Pb, P1s, P1q, gbuf);
        bn_finalize_plain<<<C2, 256, 0, stream>>>(P1s, P1q, GRID_CONV, C2, 1.f / (float)NM,
                                                  bn1_g + l * C2, bn1_b + l * C2, ss1);
        apply_g_kernel<<<GRID_APPLY, 256, 0, stream>>>(gbuf, ss1, summed, P2s, P2q);
        bn_finalize_plain<<<AF, 256, 0, stream>>>(P2s, P2q, GRID_APPLY, AF, 1.f / (float)NA,
                                                  bn2_g + l * AF, bn2_b + l * AF, ss2);
        if (l < NCONV - 1) {
            float* xnext = (xcur == x_a) ? x_b : x_a;
            spx_kernel<false><<<NA / 16, 256, 0, stream>>>(xcur, summed, ss2,
                                                           nullptr, nullptr, nullptr,
                                                           conv_W + (size_t)(l + 1) * (C2 + NBR) * C2,
                                                           conv_b + (size_t)(l + 1) * C2,
                                                           xnext, Sbuf, Pb);
            xcur = xnext;
        }
    }
    head_kernel<<<BB, 128, 0, stream>>>(xcur, summed, ss2,
                                        fc1W, fc1b, fc2W, fc2b, outW, outb, out);
}

// Round 13
// 638.379 us; speedup vs baseline: 1.5477x; 1.5477x over previous
//
#include <hip/hip_runtime.h>
#include <cmath>

#define DEV __device__ __forceinline__

constexpr int NA    = 32768;          // atoms
constexpr int M     = 12;             // neighbors
constexpr int ORIG  = 92;
constexpr int NBR   = 41;
constexpr int AF    = 64;
constexpr int C2    = 128;            // 2*AF
constexpr int HF    = 128;
constexpr int NCONV = 3;
constexpr int NM    = NA * M;         // 393216
constexpr int BB    = 1024;           // crystals
constexpr int TA    = 4;              // atoms per tile
constexpr int RT    = TA * M;         // 48 rows per tile
constexpr int NTILES = NA / TA;       // 8192
constexpr int GRID_CONV = 1024;       // full-width tile jobs (8 tiles each)
constexpr int GRID_APPLY = 1024;      // 32 atoms per block, exact cover
constexpr int WLD   = 132;            // W2 full-width row stride (128 + pad)
constexpr int ALD   = 44;             // A tile row stride (16B-aligned rows)

DEV float fsig(float x) { return __builtin_amdgcn_rcpf(1.f + __expf(-x)); }
DEV float fsp (float x) { return fmaxf(x, 0.f) + __logf(1.f + __expf(-fabsf(x))); }

DEV void fma4(float4& a, float s, const float4 w) {
    a.x = fmaf(s, w.x, a.x); a.y = fmaf(s, w.y, a.y);
    a.z = fmaf(s, w.z, a.z); a.w = fmaf(s, w.w, a.w);
}
DEV void fma2(float2& a, float s, const float2 w) {
    a.x = fmaf(s, w.x, a.x); a.y = fmaf(s, w.y, a.y);
}
DEV float comp4(const float4 v, int i) { return i == 0 ? v.x : i == 1 ? v.y : i == 2 ? v.z : v.w; }
DEV void add2(float2& a, const float2 b) { a.x += b.x; a.y += b.y; }
DEV void sqa2(float2& a, const float2 b) { a.x = fmaf(b.x, b.x, a.x); a.y = fmaf(b.y, b.y, a.y); }
DEV float2 shxor2(const float2 v, int m) {
    float2 r; r.x = __shfl_xor(v.x, m, 64); r.y = __shfl_xor(v.y, m, 64); return r;
}
DEV float4 shxor4(const float4 v, int m) {
    float4 r;
    r.x = __shfl_xor(v.x, m, 64); r.y = __shfl_xor(v.y, m, 64);
    r.z = __shfl_xor(v.z, m, 64); r.w = __shfl_xor(v.w, m, 64);
    return r;
}
DEV void add4(float4& a, const float4 b) { a.x += b.x; a.y += b.y; a.z += b.z; a.w += b.w; }
DEV unsigned bf16pair(float a, float b) {   // RNE pack: low=a, high=b
    unsigned ua = __float_as_uint(a), ub = __float_as_uint(b);
    ua += 0x7fffu + ((ua >> 16) & 1u);
    ub += 0x7fffu + ((ub >> 16) & 1u);
    return (ua >> 16) | (ub & 0xffff0000u);
}
DEV float2 up2(unsigned u) {                // unpack 2 bf16 -> float2
    float2 r;
    r.x = __uint_as_float(u << 16);
    r.y = __uint_as_float(u & 0xffff0000u);
    return r;
}

// ---- spx: x-update (embed for layer0, softplus(x+bn2(summed)) otherwise)
//      fused with S = x@W[0:64]+b (fp32) and P = x@W[64:128] (packed bf16) ----
template<bool FIRST>
__global__ __launch_bounds__(256, 4)
void spx_kernel(const float* __restrict__ xin,
                const float* __restrict__ summed,
                const float* __restrict__ ss2,
                const float* __restrict__ atom_fea,
                const float* __restrict__ embW,
                const float* __restrict__ embb,
                const float* __restrict__ W,
                const float* __restrict__ bias,
                float* __restrict__ xout,
                float* __restrict__ S,
                unsigned* __restrict__ Pb)
{
    __shared__ float xs[16][AF];
    __shared__ float af[FIRST ? 16 * ORIG : 4];

    const int a0 = blockIdx.x * 16, tid = threadIdx.x;

    if (FIRST) {
        for (int i = tid; i < 16 * ORIG; i += 256) af[i] = atom_fea[(size_t)a0 * ORIG + i];
        __syncthreads();
        const int row = tid >> 4, c4 = (tid & 15) * 4;
        float4 acc = *(const float4*)(embb + c4);
        #pragma unroll 4
        for (int k = 0; k < ORIG; ++k)
            fma4(acc, af[row * ORIG + k], *(const float4*)(embW + k * AF + c4));
        *(float4*)&xs[row][c4] = acc;
        *(float4*)(xout + (size_t)(a0 + row) * AF + c4) = acc;
    } else {
        const int row = tid >> 4, c4 = (tid & 15) * 4;
        const size_t o = (size_t)(a0 + row) * AF + c4;
        const float4 xi = *(const float4*)(xin + o);
        const float4 sm = *(const float4*)(summed + o);
        const float4 sc = *(const float4*)(ss2 + c4);
        const float4 sh = *(const float4*)(ss2 + AF + c4);
        float4 ov;
        ov.x = fsp(xi.x + fmaf(sm.x, sc.x, sh.x));
        ov.y = fsp(xi.y + fmaf(sm.y, sc.y, sh.y));
        ov.z = fsp(xi.z + fmaf(sm.z, sc.z, sh.z));
        ov.w = fsp(xi.w + fmaf(sm.w, sc.w, sh.w));
        *(float4*)&xs[row][c4] = ov;
        *(float4*)(xout + o) = ov;
    }
    __syncthreads();

    const int cid = tid & 31, rid = tid >> 5;
    const int c0 = cid * 8, r0 = rid * 2;
    const bool isS = (c0 < 128);
    const int cc = c0 & 127;
    const float* Wb = W + (isS ? 0 : AF * C2) + cc;
    float4 a00, a01, a10, a11;
    if (isS) { a00 = *(const float4*)(bias + cc); a01 = *(const float4*)(bias + cc + 4); }
    else     { a00 = {0,0,0,0}; a01 = {0,0,0,0}; }
    a10 = a00; a11 = a01;
    for (int k = 0; k < AF; ++k) {
        const float4 w0 = *(const float4*)(Wb + k * C2);
        const float4 w1 = *(const float4*)(Wb + k * C2 + 4);
        const float x0 = xs[r0][k], x1 = xs[r0 + 1][k];
        fma4(a00, x0, w0); fma4(a01, x0, w1);
        fma4(a10, x1, w0); fma4(a11, x1, w1);
    }
    if (isS) {
        *(float4*)(S + (size_t)(a0 + r0) * C2 + cc)     = a00;
        *(float4*)(S + (size_t)(a0 + r0) * C2 + cc + 4) = a01;
        *(float4*)(S + (size_t)(a0 + r0 + 1) * C2 + cc)     = a10;
        *(float4*)(S + (size_t)(a0 + r0 + 1) * C2 + cc + 4) = a11;
    } else {
        uint4 u0, u1;
        u0.x = bf16pair(a00.x, a00.y); u0.y = bf16pair(a00.z, a00.w);
        u0.z = bf16pair(a01.x, a01.y); u0.w = bf16pair(a01.z, a01.w);
        u1.x = bf16pair(a10.x, a10.y); u1.y = bf16pair(a10.z, a10.w);
        u1.z = bf16pair(a11.x, a11.y); u1.w = bf16pair(a11.z, a11.w);
        *(uint4*)(Pb + (size_t)(a0 + r0) * 64 + cc / 2)     = u0;
        *(uint4*)(Pb + (size_t)(a0 + r0 + 1) * 64 + cc / 2) = u1;
    }
}

// ------- conv stats pass, FULL-WIDTH, 8 tiles/block (R10-verified version;
//   R11/R12's single-barrier double-buffer + unroll-2 spilled ~1.4KB/thread
//   of scratch: FETCH 89->287MB, WRITE 104->462MB, 85->210us. Implicit
//   wave-level TLP already overlaps st prefetch with the GEMM here). ----
__global__ __launch_bounds__(256, 4)
void conv8_kernel(const float* __restrict__ nbr_fea,
                  const int* __restrict__ idx,
                  const float* __restrict__ W2,
                  const float* __restrict__ S,
                  const unsigned* __restrict__ Pb,
                  float* __restrict__ P1s, float* __restrict__ P1q,
                  unsigned* __restrict__ gout)
{
    __shared__ float W2h[NBR * WLD];     // 21.6 KB (full width)
    __shared__ float sA[RT * ALD];       // 8.45 KB

    const int tid  = threadIdx.x;
    const int cid  = tid & 31;           // col pair (2 filter + 2 core)
    const int rid  = tid >> 5;           // 8 row groups x 6 edges
    const int c2   = cid * 2;
    const int r0   = rid * 6;            // first edge row of this thread
    const int atom = rid >> 1;           // 6|12 -> all 6 edges share one atom

    const int q0 = blockIdx.x;

    int j[6];
    float2 svf, svc;
    float st[8];
    {
        const int n0 = q0 * TA;
        const int ib = n0 * M + r0;
        #pragma unroll
        for (int e = 0; e < 6; ++e) j[e] = idx[ib + e];
        svf = *(const float2*)(S + (size_t)(n0 + atom) * C2 + c2);
        svc = *(const float2*)(S + (size_t)(n0 + atom) * C2 + 64 + c2);
        const float* src = nbr_fea + (size_t)n0 * M * NBR;
        #pragma unroll
        for (int i = 0; i < 8; ++i)
            if (i < 7 || tid + 256 * i < RT * NBR) st[i] = src[tid + 256 * i];
    }

    // stage W2h full width (contiguous copy)
    for (int i = tid; i < NBR * 32; i += 256) {
        const int k = i >> 5, q = i & 31;
        *(float4*)&W2h[k * WLD + q * 4] = *(const float4*)(W2 + k * C2 + q * 4);
    }

    float2 sum_f = {0,0}, sum_c = {0,0}, sq_f = {0,0}, sq_c = {0,0};

    for (int it = 0; it < 8; ++it) {
        const int t  = q0 + it * GRID_CONV;
        const int n0 = t * TA;

        __syncthreads();                 // prev tile LDS fully consumed (+W2h on it=0)
        #pragma unroll
        for (int i = 0; i < 8; ++i) {
            const int e = tid + 256 * i;
            if (i < 7 || e < RT * NBR) {
                const int r = (int)(((unsigned)e * 102301u) >> 22);   // e/41
                sA[r * ALD + (e - r * NBR)] = st[i];
            }
        }
        __syncthreads();

        unsigned uf[6], uc[6];
        #pragma unroll
        for (int e = 0; e < 6; ++e) {
            uf[e] = Pb[(size_t)j[e] * 64 + cid];
            uc[e] = Pb[(size_t)j[e] * 64 + 32 + cid];
        }
        const float2 cf = svf, cc = svc;

        if (it < 7) {
            const int nn0 = (t + GRID_CONV) * TA;
            const int ib = nn0 * M + r0;
            #pragma unroll
            for (int e = 0; e < 6; ++e) j[e] = idx[ib + e];
            svf = *(const float2*)(S + (size_t)(nn0 + atom) * C2 + c2);
            svc = *(const float2*)(S + (size_t)(nn0 + atom) * C2 + 64 + c2);
            const float* src = nbr_fea + (size_t)nn0 * M * NBR;
            #pragma unroll
            for (int i = 0; i < 8; ++i)
                if (i < 7 || tid + 256 * i < RT * NBR) st[i] = src[tid + 256 * i];
        }

        float2 ef0 = {0,0}, ef1 = {0,0}, ef2 = {0,0}, ef3 = {0,0}, ef4 = {0,0}, ef5 = {0,0};
        float2 ec0 = {0,0}, ec1 = {0,0}, ec2 = {0,0}, ec3 = {0,0}, ec4 = {0,0}, ec5 = {0,0};
        const float* Ab = sA + r0 * ALD;
        #pragma unroll 2
        for (int k4 = 0; k4 < 10; ++k4) {
            const float4 a0 = *(const float4*)(Ab + 0 * ALD + k4 * 4);
            const float4 a1 = *(const float4*)(Ab + 1 * ALD + k4 * 4);
            const float4 a2 = *(const float4*)(Ab + 2 * ALD + k4 * 4);
            const float4 a3 = *(const float4*)(Ab + 3 * ALD + k4 * 4);
            const float4 a4 = *(const float4*)(Ab + 4 * ALD + k4 * 4);
            const float4 a5 = *(const float4*)(Ab + 5 * ALD + k4 * 4);
            #pragma unroll
            for (int kk = 0; kk < 4; ++kk) {
                const int k = 4 * k4 + kk;
                const float2 wf = *(const float2*)(W2h + k * WLD + c2);
                const float2 wc = *(const float2*)(W2h + k * WLD + 64 + c2);
                fma2(ef0, comp4(a0, kk), wf); fma2(ec0, comp4(a0, kk), wc);
                fma2(ef1, comp4(a1, kk), wf); fma2(ec1, comp4(a1, kk), wc);
                fma2(ef2, comp4(a2, kk), wf); fma2(ec2, comp4(a2, kk), wc);
                fma2(ef3, comp4(a3, kk), wf); fma2(ec3, comp4(a3, kk), wc);
                fma2(ef4, comp4(a4, kk), wf); fma2(ec4, comp4(a4, kk), wc);
                fma2(ef5, comp4(a5, kk), wf); fma2(ec5, comp4(a5, kk), wc);
            }
        }
        {   // k = 40
            const float2 wf = *(const float2*)(W2h + 40 * WLD + c2);
            const float2 wc = *(const float2*)(W2h + 40 * WLD + 64 + c2);
            const float b0 = Ab[0 * ALD + 40], b1 = Ab[1 * ALD + 40], b2 = Ab[2 * ALD + 40];
            const float b3 = Ab[3 * ALD + 40], b4 = Ab[4 * ALD + 40], b5 = Ab[5 * ALD + 40];
            fma2(ef0, b0, wf); fma2(ec0, b0, wc);
            fma2(ef1, b1, wf); fma2(ec1, b1, wc);
            fma2(ef2, b2, wf); fma2(ec2, b2, wc);
            fma2(ef3, b3, wf); fma2(ec3, b3, wc);
            fma2(ef4, b4, wf); fma2(ec4, b4, wc);
            fma2(ef5, b5, wf); fma2(ec5, b5, wc);
        }

        const size_t row0 = (size_t)(n0 * M + r0) * 64 + cid;
        {
            add2(ef0, cf); add2(ef0, up2(uf[0])); add2(ec0, cc); add2(ec0, up2(uc[0]));
            add2(ef1, cf); add2(ef1, up2(uf[1])); add2(ec1, cc); add2(ec1, up2(uc[1]));
            add2(ef2, cf); add2(ef2, up2(uf[2])); add2(ec2, cc); add2(ec2, up2(uc[2]));
            add2(ef3, cf); add2(ef3, up2(uf[3])); add2(ec3, cc); add2(ec3, up2(uc[3]));
            add2(ef4, cf); add2(ef4, up2(uf[4])); add2(ec4, cc); add2(ec4, up2(uc[4]));
            add2(ef5, cf); add2(ef5, up2(uf[5])); add2(ec5, cc); add2(ec5, up2(uc[5]));
            gout[row0 + 0 * 64]      = bf16pair(ef0.x, ef0.y);
            gout[row0 + 0 * 64 + 32] = bf16pair(ec0.x, ec0.y);
            gout[row0 + 1 * 64]      = bf16pair(ef1.x, ef1.y);
            gout[row0 + 1 * 64 + 32] = bf16pair(ec1.x, ec1.y);
            gout[row0 + 2 * 64]      = bf16pair(ef2.x, ef2.y);
            gout[row0 + 2 * 64 + 32] = bf16pair(ec2.x, ec2.y);
            gout[row0 + 3 * 64]      = bf16pair(ef3.x, ef3.y);
            gout[row0 + 3 * 64 + 32] = bf16pair(ec3.x, ec3.y);
            gout[row0 + 4 * 64]      = bf16pair(ef4.x, ef4.y);
            gout[row0 + 4 * 64 + 32] = bf16pair(ec4.x, ec4.y);
            gout[row0 + 5 * 64]      = bf16pair(ef5.x, ef5.y);
            gout[row0 + 5 * 64 + 32] = bf16pair(ec5.x, ec5.y);
            add2(sum_f, ef0); add2(sum_f, ef1); add2(sum_f, ef2);
            add2(sum_f, ef3); add2(sum_f, ef4); add2(sum_f, ef5);
            add2(sum_c, ec0); add2(sum_c, ec1); add2(sum_c, ec2);
            add2(sum_c, ec3); add2(sum_c, ec4); add2(sum_c, ec5);
            sqa2(sq_f, ef0); sqa2(sq_f, ef1); sqa2(sq_f, ef2);
            sqa2(sq_f, ef3); sqa2(sq_f, ef4); sqa2(sq_f, ef5);
            sqa2(sq_c, ec0); sqa2(sq_c, ec1); sqa2(sq_c, ec2);
            sqa2(sq_c, ec3); sqa2(sq_c, ec4); sqa2(sq_c, ec5);
        }
    }

    // block reduce: xor32 sums the 2 rids in each wave, then across 4 waves via sA
    { float2 t2 = shxor2(sum_f, 32); add2(sum_f, t2); }
    { float2 t2 = shxor2(sum_c, 32); add2(sum_c, t2); }
    { float2 t2 = shxor2(sq_f, 32);  add2(sq_f, t2);  }
    { float2 t2 = shxor2(sq_c, 32);  add2(sq_c, t2);  }
    __syncthreads();                 // sA free (all tiles done)
    const int w = tid >> 6;
    if ((tid & 32) == 0) {
        *(float2*)&sA[w * 128 + c2]            = sum_f;
        *(float2*)&sA[w * 128 + 64 + c2]       = sum_c;
        *(float2*)&sA[512 + w * 128 + c2]      = sq_f;
        *(float2*)&sA[512 + w * 128 + 64 + c2] = sq_c;
    }
    __syncthreads();
    if (tid < 128) {
        P1s[(size_t)blockIdx.x * C2 + tid] = sA[tid] + sA[128 + tid] + sA[256 + tid] + sA[384 + tid];
        P1q[(size_t)blockIdx.x * C2 + tid] = sA[512 + tid] + sA[640 + tid]
                                           + sA[768 + tid] + sA[896 + tid];
    }
}

// ---- apply pass (R10): uint4 (16B) loads, 8 threads/atom, 32 atoms/block ----
__global__ __launch_bounds__(256)
void apply_g_kernel(const unsigned* __restrict__ g,
                    const float* __restrict__ ss1,
                    float* __restrict__ summed,
                    float* __restrict__ P2s, float* __restrict__ P2q)
{
    const int tid = threadIdx.x;
    const int al  = tid >> 3;            // 32 atoms per block
    const int c   = tid & 7;             // col octet: cols 8c..8c+7
    const int c8  = 8 * c;

    const float4 scf0 = *(const float4*)(ss1 + c8);
    const float4 scf1 = *(const float4*)(ss1 + c8 + 4);
    const float4 scc0 = *(const float4*)(ss1 + 64 + c8);
    const float4 scc1 = *(const float4*)(ss1 + 64 + c8 + 4);
    const float4 shf0 = *(const float4*)(ss1 + C2 + c8);
    const float4 shf1 = *(const float4*)(ss1 + C2 + c8 + 4);
    const float4 shc0 = *(const float4*)(ss1 + C2 + 64 + c8);
    const float4 shc1 = *(const float4*)(ss1 + C2 + 64 + c8 + 4);

    const int a = blockIdx.x * 32 + al;
    const unsigned* gr = g + (size_t)a * M * 64 + 4 * c;
    float4 acc0 = {0,0,0,0}, acc1 = {0,0,0,0};
    #pragma unroll
    for (int m = 0; m < M; ++m) {
        const uint4 uf = *(const uint4*)(gr + m * 64);
        const uint4 uc = *(const uint4*)(gr + m * 64 + 32);
        const float2 f0 = up2(uf.x), f1 = up2(uf.y), f2 = up2(uf.z), f3 = up2(uf.w);
        const float2 s0 = up2(uc.x), s1 = up2(uc.y), s2 = up2(uc.z), s3 = up2(uc.w);
        acc0.x = fmaf(fsig(fmaf(f0.x, scf0.x, shf0.x)), fsp(fmaf(s0.x, scc0.x, shc0.x)), acc0.x);
        acc0.y = fmaf(fsig(fmaf(f0.y, scf0.y, shf0.y)), fsp(fmaf(s0.y, scc0.y, shc0.y)), acc0.y);
        acc0.z = fmaf(fsig(fmaf(f1.x, scf0.z, shf0.z)), fsp(fmaf(s1.x, scc0.z, shc0.z)), acc0.z);
        acc0.w = fmaf(fsig(fmaf(f1.y, scf0.w, shf0.w)), fsp(fmaf(s1.y, scc0.w, shc0.w)), acc0.w);
        acc1.x = fmaf(fsig(fmaf(f2.x, scf1.x, shf1.x)), fsp(fmaf(s2.x, scc1.x, shc1.x)), acc1.x);
        acc1.y = fmaf(fsig(fmaf(f2.y, scf1.y, shf1.y)), fsp(fmaf(s2.y, scc1.y, shc1.y)), acc1.y);
        acc1.z = fmaf(fsig(fmaf(f3.x, scf1.z, shf1.z)), fsp(fmaf(s3.x, scc1.z, shc1.z)), acc1.z);
        acc1.w = fmaf(fsig(fmaf(f3.y, scf1.w, shf1.w)), fsp(fmaf(s3.y, scc1.w, shc1.w)), acc1.w);
    }
    *(float4*)(summed + (size_t)a * AF + c8)     = acc0;
    *(float4*)(summed + (size_t)a * AF + c8 + 4) = acc1;

    // BN2 partials: squares, then wave xor-reduce over the 8 atoms in the wave
    float4 tq0, tq1;
    tq0.x = acc0.x * acc0.x; tq0.y = acc0.y * acc0.y;
    tq0.z = acc0.z * acc0.z; tq0.w = acc0.w * acc0.w;
    tq1.x = acc1.x * acc1.x; tq1.y = acc1.y * acc1.y;
    tq1.z = acc1.z * acc1.z; tq1.w = acc1.w * acc1.w;
    float4 ts0 = acc0, ts1 = acc1;
    #pragma unroll
    for (int msk = 8; msk <= 32; msk <<= 1) {
        add4(ts0, shxor4(ts0, msk));
        add4(ts1, shxor4(ts1, msk));
        add4(tq0, shxor4(tq0, msk));
        add4(tq1, shxor4(tq1, msk));
    }

    __shared__ float ws[4][8][16];       // [wave][col-octet][ts0..7, tq0..7]
    if ((tid & 63) < 8) {
        float* d = &ws[tid >> 6][c][0];
        *(float4*)(d)      = ts0;
        *(float4*)(d + 4)  = ts1;
        *(float4*)(d + 8)  = tq0;
        *(float4*)(d + 12) = tq1;
    }
    __syncthreads();
    if (tid < 64) {
        const int c_ = tid >> 3, o = tid & 7;
        const float s = ws[0][c_][o] + ws[1][c_][o] + ws[2][c_][o] + ws[3][c_][o];
        const float q = ws[0][c_][8 + o] + ws[1][c_][8 + o]
                      + ws[2][c_][8 + o] + ws[3][c_][8 + o];
        P2s[(size_t)blockIdx.x * AF + tid] = s;
        P2q[(size_t)blockIdx.x * AF + tid] = q;
    }
}

// ---- plain BN finalize (BN1 & BN2): partials [npart][C] ----
__global__ __launch_bounds__(256)
void bn_finalize_plain(const float* __restrict__ Ps, const float* __restrict__ Pq,
                       int npart, int C, float invn,
                       const float* __restrict__ gamma, const float* __restrict__ beta,
                       float* __restrict__ ss)
{
    __shared__ float sd[256];
    const int c = blockIdx.x, tid = threadIdx.x;
    float s = 0.f;
    for (int j = tid; j < npart; j += 256) s += Ps[(size_t)j * C + c];
    sd[tid] = s; __syncthreads();
    for (int st = 128; st > 0; st >>= 1) { if (tid < st) sd[tid] += sd[tid + st]; __syncthreads(); }
    const float total = sd[0];
    __syncthreads();
    float q = 0.f;
    for (int j = tid; j < npart; j += 256) q += Pq[(size_t)j * C + c];
    sd[tid] = q; __syncthreads();
    for (int st = 128; st > 0; st >>= 1) { if (tid < st) sd[tid] += sd[tid + st]; __syncthreads(); }
    if (tid == 0) {
        const float mean = total * invn;
        const float var  = sd[0] * invn - mean * mean;
        const float scl  = gamma[c] * rsqrtf(var + 1e-5f);
        ss[c]     = scl;
        ss[C + c] = beta[c] - mean * scl;
    }
}

// ---------------- head: fused x-update + pool + MLP ----------------
__global__ __launch_bounds__(128)
void head_kernel(const float* __restrict__ x,
                 const float* __restrict__ summed,
                 const float* __restrict__ ss2,
                 const float* __restrict__ fc1W, const float* __restrict__ fc1b,
                 const float* __restrict__ fc2W, const float* __restrict__ fc2b,
                 const float* __restrict__ outW, const float* __restrict__ outb,
                 float* __restrict__ out)
{
    __shared__ float l0[AF], l1[HF], rr[2], hs[2][AF];
    const int b = blockIdx.x, tid = threadIdx.x;
    const int col = tid & 63, half = tid >> 6;
    {
        const float sc = ss2[col], sh = ss2[AF + col];
        float s = 0.f;
        #pragma unroll 4
        for (int a = half * 16; a < half * 16 + 16; ++a) {
            const size_t o = (size_t)(b * 32 + a) * AF + col;
            s += fsp(x[o] + fmaf(summed[o], sc, sh));
        }
        hs[half][col] = s;
    }
    __syncthreads();
    if (tid < AF) l0[tid] = fsp((hs[0][tid] + hs[1][tid]) * (1.f / 32.f));
    __syncthreads();
    float acc = fc1b[tid];
    #pragma unroll 4
    for (int k = 0; k < AF; ++k) acc = fmaf(l0[k], fc1W[k * HF + tid], acc);
    l1[tid] = fsp(acc);
    __syncthreads();
    acc = fc2b[tid];
    #pragma unroll 4
    for (int k = 0; k < HF; ++k) acc = fmaf(l1[k], fc2W[k * HF + tid], acc);
    float v = fsp(acc) * outW[tid];
    #pragma unroll
    for (int off = 32; off > 0; off >>= 1) v += __shfl_down(v, off, 64);
    if ((tid & 63) == 0) rr[tid >> 6] = v;
    __syncthreads();
    if (tid == 0) out[b] = rr[0] + rr[1] + outb[0];
}

extern "C" void kernel_launch(void* const* d_in, const int* in_sizes, int n_in,
                              void* d_out, int out_size, void* d_ws, size_t ws_size,
                              hipStream_t stream)
{
    const float* atom_fea = (const float*)d_in[0];
    const float* nbr_fea  = (const float*)d_in[1];
    const int*   nbr_idx  = (const int*)d_in[2];
    const float* emb_W  = (const float*)d_in[4];
    const float* emb_b  = (const float*)d_in[5];
    const float* conv_W = (const float*)d_in[6];
    const float* conv_b = (const float*)d_in[7];
    const float* bn1_g  = (const float*)d_in[8];
    const float* bn1_b  = (const float*)d_in[9];
    const float* bn2_g  = (const float*)d_in[10];
    const float* bn2_b  = (const float*)d_in[11];
    const float* fc1W   = (const float*)d_in[12];
    const float* fc1b   = (const float*)d_in[13];
    const float* fc2W   = (const float*)d_in[14];
    const float* fc2b   = (const float*)d_in[15];
    const float* outW   = (const float*)d_in[16];
    const float* outb   = (const float*)d_in[17];
    float* out = (float*)d_out;
    float* ws  = (float*)d_ws;

    // workspace (~145 MB)
    float*    x_a    = ws;
    float*    x_b    = x_a + (size_t)NA * AF;
    float*    Sbuf   = x_b + (size_t)NA * AF;
    unsigned* Pb     = (unsigned*)(Sbuf + (size_t)NA * C2);   // NA x 64 uints (bf16 pairs)
    float*    summed = (float*)(Pb + (size_t)NA * 64);
    float*    P1s    = summed + (size_t)NA * AF;              // [1024][128]
    float*    P1q    = P1s + (size_t)GRID_CONV * C2;
    float*    P2s    = P1q + (size_t)GRID_CONV * C2;          // [1024][64]
    float*    P2q    = P2s + (size_t)GRID_APPLY * AF;
    float*    ss1    = P2q + (size_t)GRID_APPLY * AF;
    float*    ss2    = ss1 + 2 * C2;
    unsigned* gbuf   = (unsigned*)(ss2 + 2 * AF);             // NM x 64 uints (bf16 pairs)

    float* xcur = x_a;
    spx_kernel<true><<<NA / 16, 256, 0, stream>>>(nullptr, nullptr, nullptr,
                                                  atom_fea, emb_W, emb_b,
                                                  conv_W, conv_b, xcur, Sbuf, Pb);
    for (int l = 0; l < NCONV; ++l) {
        const float* W2 = conv_W + (size_t)l * (C2 + NBR) * C2 + (size_t)C2 * C2;
        conv8_kernel<<<GRID_CONV, 256, 0, stream>>>(nbr_fea, nbr_idx, W2,
                                                    Sbuf, Pb, P1s, P1q, gbuf);
        bn_finalize_plain<<<C2, 256, 0, stream>>>(P1s, P1q, GRID_CONV, C2, 1.f / (float)NM,
                                                  bn1_g + l * C2, bn1_b + l * C2, ss1);
        apply_g_kernel<<<GRID_APPLY, 256, 0, stream>>>(gbuf, ss1, summed, P2s, P2q);
        bn_finalize_plain<<<AF, 256, 0, stream>>>(P2s, P2q, GRID_APPLY, AF, 1.f / (float)NA,
                                                  bn2_g + l * AF, bn2_b + l * AF, ss2);
        if (l < NCONV - 1) {
            float* xnext = (xcur == x_a) ? x_b : x_a;
            spx_kernel<false><<<NA / 16, 256, 0, stream>>>(xcur, summed, ss2,
                                                           nullptr, nullptr, nullptr,
                                                           conv_W + (size_t)(l + 1) * (C2 + NBR) * C2,
                                                           conv_b + (size_t)(l + 1) * C2,
                                                           xnext, Sbuf, Pb);
            xcur = xnext;
        }
    }
    head_kernel<<<BB, 128, 0, stream>>>(xcur, summed, ss2,
                                        fc1W, fc1b, fc2W, fc2b, outW, outb, out);
}

// Round 14
// 600.256 us; speedup vs baseline: 1.6460x; 1.0635x over previous
//
#include <hip/hip_runtime.h>
#include <cmath>

#define DEV __device__ __forceinline__

constexpr int NA    = 32768;          // atoms
constexpr int M     = 12;             // neighbors
constexpr int ORIG  = 92;
constexpr int NBR   = 41;
constexpr int AF    = 64;
constexpr int C2    = 128;            // 2*AF
constexpr int HF    = 128;
constexpr int NCONV = 3;
constexpr int NM    = NA * M;         // 393216
constexpr int BB    = 1024;           // crystals
constexpr int TA    = 4;              // atoms per tile
constexpr int RT    = TA * M;         // 48 rows per tile
constexpr int NTILES = NA / TA;       // 8192
constexpr int GRID_CONV = 1024;       // full-width tile jobs (8 tiles each)
constexpr int GRID_APPLY = 2048;      // 16 atoms per block, M split across 2 threads
constexpr int WLD   = 132;            // W2 full-width row stride (128 + pad)
constexpr int ALD   = 44;             // A tile row stride (16B-aligned rows)

DEV float fsig(float x) { return __builtin_amdgcn_rcpf(1.f + __expf(-x)); }
DEV float fsp (float x) { return fmaxf(x, 0.f) + __logf(1.f + __expf(-fabsf(x))); }

DEV void fma4(float4& a, float s, const float4 w) {
    a.x = fmaf(s, w.x, a.x); a.y = fmaf(s, w.y, a.y);
    a.z = fmaf(s, w.z, a.z); a.w = fmaf(s, w.w, a.w);
}
DEV void fma2(float2& a, float s, const float2 w) {
    a.x = fmaf(s, w.x, a.x); a.y = fmaf(s, w.y, a.y);
}
DEV float comp4(const float4 v, int i) { return i == 0 ? v.x : i == 1 ? v.y : i == 2 ? v.z : v.w; }
DEV void add2(float2& a, const float2 b) { a.x += b.x; a.y += b.y; }
DEV void sqa2(float2& a, const float2 b) { a.x = fmaf(b.x, b.x, a.x); a.y = fmaf(b.y, b.y, a.y); }
DEV float2 shxor2(const float2 v, int m) {
    float2 r; r.x = __shfl_xor(v.x, m, 64); r.y = __shfl_xor(v.y, m, 64); return r;
}
DEV float4 shxor4(const float4 v, int m) {
    float4 r;
    r.x = __shfl_xor(v.x, m, 64); r.y = __shfl_xor(v.y, m, 64);
    r.z = __shfl_xor(v.z, m, 64); r.w = __shfl_xor(v.w, m, 64);
    return r;
}
DEV void add4(float4& a, const float4 b) { a.x += b.x; a.y += b.y; a.z += b.z; a.w += b.w; }
DEV unsigned bf16pair(float a, float b) {   // RNE pack: low=a, high=b
    unsigned ua = __float_as_uint(a), ub = __float_as_uint(b);
    ua += 0x7fffu + ((ua >> 16) & 1u);
    ub += 0x7fffu + ((ub >> 16) & 1u);
    return (ua >> 16) | (ub & 0xffff0000u);
}
DEV float2 up2(unsigned u) {                // unpack 2 bf16 -> float2
    float2 r;
    r.x = __uint_as_float(u << 16);
    r.y = __uint_as_float(u & 0xffff0000u);
    return r;
}

// ---- spx: x-update (embed for layer0, softplus(x+bn2(summed)) otherwise)
//      fused with S = x@W[0:64]+b (fp32) and P = x@W[64:128] (packed bf16) ----
template<bool FIRST>
__global__ __launch_bounds__(256, 4)
void spx_kernel(const float* __restrict__ xin,
                const float* __restrict__ summed,
                const float* __restrict__ ss2,
                const float* __restrict__ atom_fea,
                const float* __restrict__ embW,
                const float* __restrict__ embb,
                const float* __restrict__ W,
                const float* __restrict__ bias,
                float* __restrict__ xout,
                float* __restrict__ S,
                unsigned* __restrict__ Pb)
{
    __shared__ float xs[16][AF];
    __shared__ float af[FIRST ? 16 * ORIG : 4];

    const int a0 = blockIdx.x * 16, tid = threadIdx.x;

    if (FIRST) {
        for (int i = tid; i < 16 * ORIG; i += 256) af[i] = atom_fea[(size_t)a0 * ORIG + i];
        __syncthreads();
        const int row = tid >> 4, c4 = (tid & 15) * 4;
        float4 acc = *(const float4*)(embb + c4);
        #pragma unroll 4
        for (int k = 0; k < ORIG; ++k)
            fma4(acc, af[row * ORIG + k], *(const float4*)(embW + k * AF + c4));
        *(float4*)&xs[row][c4] = acc;
        *(float4*)(xout + (size_t)(a0 + row) * AF + c4) = acc;
    } else {
        const int row = tid >> 4, c4 = (tid & 15) * 4;
        const size_t o = (size_t)(a0 + row) * AF + c4;
        const float4 xi = *(const float4*)(xin + o);
        const float4 sm = *(const float4*)(summed + o);
        const float4 sc = *(const float4*)(ss2 + c4);
        const float4 sh = *(const float4*)(ss2 + AF + c4);
        float4 ov;
        ov.x = fsp(xi.x + fmaf(sm.x, sc.x, sh.x));
        ov.y = fsp(xi.y + fmaf(sm.y, sc.y, sh.y));
        ov.z = fsp(xi.z + fmaf(sm.z, sc.z, sh.z));
        ov.w = fsp(xi.w + fmaf(sm.w, sc.w, sh.w));
        *(float4*)&xs[row][c4] = ov;
        *(float4*)(xout + o) = ov;
    }
    __syncthreads();

    const int cid = tid & 31, rid = tid >> 5;
    const int c0 = cid * 8, r0 = rid * 2;
    const bool isS = (c0 < 128);
    const int cc = c0 & 127;
    const float* Wb = W + (isS ? 0 : AF * C2) + cc;
    float4 a00, a01, a10, a11;
    if (isS) { a00 = *(const float4*)(bias + cc); a01 = *(const float4*)(bias + cc + 4); }
    else     { a00 = {0,0,0,0}; a01 = {0,0,0,0}; }
    a10 = a00; a11 = a01;
    for (int k = 0; k < AF; ++k) {
        const float4 w0 = *(const float4*)(Wb + k * C2);
        const float4 w1 = *(const float4*)(Wb + k * C2 + 4);
        const float x0 = xs[r0][k], x1 = xs[r0 + 1][k];
        fma4(a00, x0, w0); fma4(a01, x0, w1);
        fma4(a10, x1, w0); fma4(a11, x1, w1);
    }
    if (isS) {
        *(float4*)(S + (size_t)(a0 + r0) * C2 + cc)     = a00;
        *(float4*)(S + (size_t)(a0 + r0) * C2 + cc + 4) = a01;
        *(float4*)(S + (size_t)(a0 + r0 + 1) * C2 + cc)     = a10;
        *(float4*)(S + (size_t)(a0 + r0 + 1) * C2 + cc + 4) = a11;
    } else {
        uint4 u0, u1;
        u0.x = bf16pair(a00.x, a00.y); u0.y = bf16pair(a00.z, a00.w);
        u0.z = bf16pair(a01.x, a01.y); u0.w = bf16pair(a01.z, a01.w);
        u1.x = bf16pair(a10.x, a10.y); u1.y = bf16pair(a10.z, a10.w);
        u1.z = bf16pair(a11.x, a11.y); u1.w = bf16pair(a11.z, a11.w);
        *(uint4*)(Pb + (size_t)(a0 + r0) * 64 + cc / 2)     = u0;
        *(uint4*)(Pb + (size_t)(a0 + r0 + 1) * 64 + cc / 2) = u1;
    }
}

// ------- conv stats pass, FULL-WIDTH, 8 tiles/block (R10-verified version) ----
__global__ __launch_bounds__(256, 4)
void conv8_kernel(const float* __restrict__ nbr_fea,
                  const int* __restrict__ idx,
                  const float* __restrict__ W2,
                  const float* __restrict__ S,
                  const unsigned* __restrict__ Pb,
                  float* __restrict__ P1s, float* __restrict__ P1q,
                  unsigned* __restrict__ gout)
{
    __shared__ float W2h[NBR * WLD];     // 21.6 KB (full width)
    __shared__ float sA[RT * ALD];       // 8.45 KB

    const int tid  = threadIdx.x;
    const int cid  = tid & 31;           // col pair (2 filter + 2 core)
    const int rid  = tid >> 5;           // 8 row groups x 6 edges
    const int c2   = cid * 2;
    const int r0   = rid * 6;            // first edge row of this thread
    const int atom = rid >> 1;           // 6|12 -> all 6 edges share one atom

    const int q0 = blockIdx.x;

    int j[6];
    float2 svf, svc;
    float st[8];
    {
        const int n0 = q0 * TA;
        const int ib = n0 * M + r0;
        #pragma unroll
        for (int e = 0; e < 6; ++e) j[e] = idx[ib + e];
        svf = *(const float2*)(S + (size_t)(n0 + atom) * C2 + c2);
        svc = *(const float2*)(S + (size_t)(n0 + atom) * C2 + 64 + c2);
        const float* src = nbr_fea + (size_t)n0 * M * NBR;
        #pragma unroll
        for (int i = 0; i < 8; ++i)
            if (i < 7 || tid + 256 * i < RT * NBR) st[i] = src[tid + 256 * i];
    }

    // stage W2h full width (contiguous copy)
    for (int i = tid; i < NBR * 32; i += 256) {
        const int k = i >> 5, q = i & 31;
        *(float4*)&W2h[k * WLD + q * 4] = *(const float4*)(W2 + k * C2 + q * 4);
    }

    float2 sum_f = {0,0}, sum_c = {0,0}, sq_f = {0,0}, sq_c = {0,0};

    for (int it = 0; it < 8; ++it) {
        const int t  = q0 + it * GRID_CONV;
        const int n0 = t * TA;

        __syncthreads();                 // prev tile LDS fully consumed (+W2h on it=0)
        #pragma unroll
        for (int i = 0; i < 8; ++i) {
            const int e = tid + 256 * i;
            if (i < 7 || e < RT * NBR) {
                const int r = (int)(((unsigned)e * 102301u) >> 22);   // e/41
                sA[r * ALD + (e - r * NBR)] = st[i];
            }
        }
        __syncthreads();

        unsigned uf[6], uc[6];
        #pragma unroll
        for (int e = 0; e < 6; ++e) {
            uf[e] = Pb[(size_t)j[e] * 64 + cid];
            uc[e] = Pb[(size_t)j[e] * 64 + 32 + cid];
        }
        const float2 cf = svf, cc = svc;

        if (it < 7) {
            const int nn0 = (t + GRID_CONV) * TA;
            const int ib = nn0 * M + r0;
            #pragma unroll
            for (int e = 0; e < 6; ++e) j[e] = idx[ib + e];
            svf = *(const float2*)(S + (size_t)(nn0 + atom) * C2 + c2);
            svc = *(const float2*)(S + (size_t)(nn0 + atom) * C2 + 64 + c2);
            const float* src = nbr_fea + (size_t)nn0 * M * NBR;
            #pragma unroll
            for (int i = 0; i < 8; ++i)
                if (i < 7 || tid + 256 * i < RT * NBR) st[i] = src[tid + 256 * i];
        }

        float2 ef0 = {0,0}, ef1 = {0,0}, ef2 = {0,0}, ef3 = {0,0}, ef4 = {0,0}, ef5 = {0,0};
        float2 ec0 = {0,0}, ec1 = {0,0}, ec2 = {0,0}, ec3 = {0,0}, ec4 = {0,0}, ec5 = {0,0};
        const float* Ab = sA + r0 * ALD;
        #pragma unroll 2
        for (int k4 = 0; k4 < 10; ++k4) {
            const float4 a0 = *(const float4*)(Ab + 0 * ALD + k4 * 4);
            const float4 a1 = *(const float4*)(Ab + 1 * ALD + k4 * 4);
            const float4 a2 = *(const float4*)(Ab + 2 * ALD + k4 * 4);
            const float4 a3 = *(const float4*)(Ab + 3 * ALD + k4 * 4);
            const float4 a4 = *(const float4*)(Ab + 4 * ALD + k4 * 4);
            const float4 a5 = *(const float4*)(Ab + 5 * ALD + k4 * 4);
            #pragma unroll
            for (int kk = 0; kk < 4; ++kk) {
                const int k = 4 * k4 + kk;
                const float2 wf = *(const float2*)(W2h + k * WLD + c2);
                const float2 wc = *(const float2*)(W2h + k * WLD + 64 + c2);
                fma2(ef0, comp4(a0, kk), wf); fma2(ec0, comp4(a0, kk), wc);
                fma2(ef1, comp4(a1, kk), wf); fma2(ec1, comp4(a1, kk), wc);
                fma2(ef2, comp4(a2, kk), wf); fma2(ec2, comp4(a2, kk), wc);
                fma2(ef3, comp4(a3, kk), wf); fma2(ec3, comp4(a3, kk), wc);
                fma2(ef4, comp4(a4, kk), wf); fma2(ec4, comp4(a4, kk), wc);
                fma2(ef5, comp4(a5, kk), wf); fma2(ec5, comp4(a5, kk), wc);
            }
        }
        {   // k = 40
            const float2 wf = *(const float2*)(W2h + 40 * WLD + c2);
            const float2 wc = *(const float2*)(W2h + 40 * WLD + 64 + c2);
            const float b0 = Ab[0 * ALD + 40], b1 = Ab[1 * ALD + 40], b2 = Ab[2 * ALD + 40];
            const float b3 = Ab[3 * ALD + 40], b4 = Ab[4 * ALD + 40], b5 = Ab[5 * ALD + 40];
            fma2(ef0, b0, wf); fma2(ec0, b0, wc);
            fma2(ef1, b1, wf); fma2(ec1, b1, wc);
            fma2(ef2, b2, wf); fma2(ec2, b2, wc);
            fma2(ef3, b3, wf); fma2(ec3, b3, wc);
            fma2(ef4, b4, wf); fma2(ec4, b4, wc);
            fma2(ef5, b5, wf); fma2(ec5, b5, wc);
        }

        const size_t row0 = (size_t)(n0 * M + r0) * 64 + cid;
        {
            add2(ef0, cf); add2(ef0, up2(uf[0])); add2(ec0, cc); add2(ec0, up2(uc[0]));
            add2(ef1, cf); add2(ef1, up2(uf[1])); add2(ec1, cc); add2(ec1, up2(uc[1]));
            add2(ef2, cf); add2(ef2, up2(uf[2])); add2(ec2, cc); add2(ec2, up2(uc[2]));
            add2(ef3, cf); add2(ef3, up2(uf[3])); add2(ec3, cc); add2(ec3, up2(uc[3]));
            add2(ef4, cf); add2(ef4, up2(uf[4])); add2(ec4, cc); add2(ec4, up2(uc[4]));
            add2(ef5, cf); add2(ef5, up2(uf[5])); add2(ec5, cc); add2(ec5, up2(uc[5]));
            gout[row0 + 0 * 64]      = bf16pair(ef0.x, ef0.y);
            gout[row0 + 0 * 64 + 32] = bf16pair(ec0.x, ec0.y);
            gout[row0 + 1 * 64]      = bf16pair(ef1.x, ef1.y);
            gout[row0 + 1 * 64 + 32] = bf16pair(ec1.x, ec1.y);
            gout[row0 + 2 * 64]      = bf16pair(ef2.x, ef2.y);
            gout[row0 + 2 * 64 + 32] = bf16pair(ec2.x, ec2.y);
            gout[row0 + 3 * 64]      = bf16pair(ef3.x, ef3.y);
            gout[row0 + 3 * 64 + 32] = bf16pair(ec3.x, ec3.y);
            gout[row0 + 4 * 64]      = bf16pair(ef4.x, ef4.y);
            gout[row0 + 4 * 64 + 32] = bf16pair(ec4.x, ec4.y);
            gout[row0 + 5 * 64]      = bf16pair(ef5.x, ef5.y);
            gout[row0 + 5 * 64 + 32] = bf16pair(ec5.x, ec5.y);
            add2(sum_f, ef0); add2(sum_f, ef1); add2(sum_f, ef2);
            add2(sum_f, ef3); add2(sum_f, ef4); add2(sum_f, ef5);
            add2(sum_c, ec0); add2(sum_c, ec1); add2(sum_c, ec2);
            add2(sum_c, ec3); add2(sum_c, ec4); add2(sum_c, ec5);
            sqa2(sq_f, ef0); sqa2(sq_f, ef1); sqa2(sq_f, ef2);
            sqa2(sq_f, ef3); sqa2(sq_f, ef4); sqa2(sq_f, ef5);
            sqa2(sq_c, ec0); sqa2(sq_c, ec1); sqa2(sq_c, ec2);
            sqa2(sq_c, ec3); sqa2(sq_c, ec4); sqa2(sq_c, ec5);
        }
    }

    // block reduce: xor32 sums the 2 rids in each wave, then across 4 waves via sA
    { float2 t2 = shxor2(sum_f, 32); add2(sum_f, t2); }
    { float2 t2 = shxor2(sum_c, 32); add2(sum_c, t2); }
    { float2 t2 = shxor2(sq_f, 32);  add2(sq_f, t2);  }
    { float2 t2 = shxor2(sq_c, 32);  add2(sq_c, t2);  }
    __syncthreads();                 // sA free (all tiles done)
    const int w = tid >> 6;
    if ((tid & 32) == 0) {
        *(float2*)&sA[w * 128 + c2]            = sum_f;
        *(float2*)&sA[w * 128 + 64 + c2]       = sum_c;
        *(float2*)&sA[512 + w * 128 + c2]      = sq_f;
        *(float2*)&sA[512 + w * 128 + 64 + c2] = sq_c;
    }
    __syncthreads();
    if (tid < 128) {
        P1s[(size_t)blockIdx.x * C2 + tid] = sA[tid] + sA[128 + tid] + sA[256 + tid] + sA[384 + tid];
        P1q[(size_t)blockIdx.x * C2 + tid] = sA[512 + tid] + sA[640 + tid]
                                           + sA[768 + tid] + sA[896 + tid];
    }
}

// ---- apply pass (R14): M-sum split across 2 threads for 2x TLP.
//   16 threads/atom = 8 col-octets x 2 m-halves; 16 atoms/block, grid 2048
//   -> 8192 waves (8/SIMD, was 4/SIMD) to hide the 12 dependent 16B loads.
//   Halves joined with one shfl_xor(8); summed written by h=0 lanes; BN2
//   stats squared AFTER the join, wave-reduced over 4 atoms (masks 16/32). ----
__global__ __launch_bounds__(256)
void apply_g_kernel(const unsigned* __restrict__ g,
                    const float* __restrict__ ss1,
                    float* __restrict__ summed,
                    float* __restrict__ P2s, float* __restrict__ P2q)
{
    const int tid = threadIdx.x;
    const int al  = tid >> 4;            // 16 atoms per block
    const int h   = (tid >> 3) & 1;      // m half
    const int c   = tid & 7;             // col octet: cols 8c..8c+7
    const int c8  = 8 * c;

    const float4 scf0 = *(const float4*)(ss1 + c8);
    const float4 scf1 = *(const float4*)(ss1 + c8 + 4);
    const float4 scc0 = *(const float4*)(ss1 + 64 + c8);
    const float4 scc1 = *(const float4*)(ss1 + 64 + c8 + 4);
    const float4 shf0 = *(const float4*)(ss1 + C2 + c8);
    const float4 shf1 = *(const float4*)(ss1 + C2 + c8 + 4);
    const float4 shc0 = *(const float4*)(ss1 + C2 + 64 + c8);
    const float4 shc1 = *(const float4*)(ss1 + C2 + 64 + c8 + 4);

    const int a = blockIdx.x * 16 + al;
    const unsigned* gr = g + (size_t)a * M * 64 + (size_t)h * 6 * 64 + 4 * c;
    float4 acc0 = {0,0,0,0}, acc1 = {0,0,0,0};
    #pragma unroll
    for (int mm = 0; mm < 6; ++mm) {
        const uint4 uf = *(const uint4*)(gr + mm * 64);
        const uint4 uc = *(const uint4*)(gr + mm * 64 + 32);
        const float2 f0 = up2(uf.x), f1 = up2(uf.y), f2 = up2(uf.z), f3 = up2(uf.w);
        const float2 s0 = up2(uc.x), s1 = up2(uc.y), s2 = up2(uc.z), s3 = up2(uc.w);
        acc0.x = fmaf(fsig(fmaf(f0.x, scf0.x, shf0.x)), fsp(fmaf(s0.x, scc0.x, shc0.x)), acc0.x);
        acc0.y = fmaf(fsig(fmaf(f0.y, scf0.y, shf0.y)), fsp(fmaf(s0.y, scc0.y, shc0.y)), acc0.y);
        acc0.z = fmaf(fsig(fmaf(f1.x, scf0.z, shf0.z)), fsp(fmaf(s1.x, scc0.z, shc0.z)), acc0.z);
        acc0.w = fmaf(fsig(fmaf(f1.y, scf0.w, shf0.w)), fsp(fmaf(s1.y, scc0.w, shc0.w)), acc0.w);
        acc1.x = fmaf(fsig(fmaf(f2.x, scf1.x, shf1.x)), fsp(fmaf(s2.x, scc1.x, shc1.x)), acc1.x);
        acc1.y = fmaf(fsig(fmaf(f2.y, scf1.y, shf1.y)), fsp(fmaf(s2.y, scc1.y, shc1.y)), acc1.y);
        acc1.z = fmaf(fsig(fmaf(f3.x, scf1.z, shf1.z)), fsp(fmaf(s3.x, scc1.z, shc1.z)), acc1.z);
        acc1.w = fmaf(fsig(fmaf(f3.y, scf1.w, shf1.w)), fsp(fmaf(s3.y, scc1.w, shc1.w)), acc1.w);
    }

    // join m-halves (lanes differing in bit 3 hold the two halves)
    add4(acc0, shxor4(acc0, 8));
    add4(acc1, shxor4(acc1, 8));
    if (h == 0) {
        *(float4*)(summed + (size_t)a * AF + c8)     = acc0;
        *(float4*)(summed + (size_t)a * AF + c8 + 4) = acc1;
    }

    // BN2 partials: square the FULL per-atom sum, reduce over 4 atoms in wave
    // (masks 16,32). h-duplicate copies collapse at the writer-lane select.
    float4 tq0, tq1;
    tq0.x = acc0.x * acc0.x; tq0.y = acc0.y * acc0.y;
    tq0.z = acc0.z * acc0.z; tq0.w = acc0.w * acc0.w;
    tq1.x = acc1.x * acc1.x; tq1.y = acc1.y * acc1.y;
    tq1.z = acc1.z * acc1.z; tq1.w = acc1.w * acc1.w;
    float4 ts0 = acc0, ts1 = acc1;
    #pragma unroll
    for (int msk = 16; msk <= 32; msk <<= 1) {
        add4(ts0, shxor4(ts0, msk));
        add4(ts1, shxor4(ts1, msk));
        add4(tq0, shxor4(tq0, msk));
        add4(tq1, shxor4(tq1, msk));
    }

    __shared__ float ws[4][8][16];       // [wave][col-octet][ts0..7, tq0..7]
    if ((tid & 63) < 8) {                // al=wave-local 0, h=0, c=0..7
        float* d = &ws[tid >> 6][c][0];
        *(float4*)(d)      = ts0;
        *(float4*)(d + 4)  = ts1;
        *(float4*)(d + 8)  = tq0;
        *(float4*)(d + 12) = tq1;
    }
    __syncthreads();
    if (tid < 64) {
        const int c_ = tid >> 3, o = tid & 7;
        const float s = ws[0][c_][o] + ws[1][c_][o] + ws[2][c_][o] + ws[3][c_][o];
        const float q = ws[0][c_][8 + o] + ws[1][c_][8 + o]
                      + ws[2][c_][8 + o] + ws[3][c_][8 + o];
        P2s[(size_t)blockIdx.x * AF + tid] = s;
        P2q[(size_t)blockIdx.x * AF + tid] = q;
    }
}

// ---- plain BN finalize (BN1 & BN2): partials [npart][C] ----
__global__ __launch_bounds__(256)
void bn_finalize_plain(const float* __restrict__ Ps, const float* __restrict__ Pq,
                       int npart, int C, float invn,
                       const float* __restrict__ gamma, const float* __restrict__ beta,
                       float* __restrict__ ss)
{
    __shared__ float sd[256];
    const int c = blockIdx.x, tid = threadIdx.x;
    float s = 0.f;
    for (int j = tid; j < npart; j += 256) s += Ps[(size_t)j * C + c];
    sd[tid] = s; __syncthreads();
    for (int st = 128; st > 0; st >>= 1) { if (tid < st) sd[tid] += sd[tid + st]; __syncthreads(); }
    const float total = sd[0];
    __syncthreads();
    float q = 0.f;
    for (int j = tid; j < npart; j += 256) q += Pq[(size_t)j * C + c];
    sd[tid] = q; __syncthreads();
    for (int st = 128; st > 0; st >>= 1) { if (tid < st) sd[tid] += sd[tid + st]; __syncthreads(); }
    if (tid == 0) {
        const float mean = total * invn;
        const float var  = sd[0] * invn - mean * mean;
        const float scl  = gamma[c] * rsqrtf(var + 1e-5f);
        ss[c]     = scl;
        ss[C + c] = beta[c] - mean * scl;
    }
}

// ---------------- head: fused x-update + pool + MLP ----------------
__global__ __launch_bounds__(128)
void head_kernel(const float* __restrict__ x,
                 const float* __restrict__ summed,
                 const float* __restrict__ ss2,
                 const float* __restrict__ fc1W, const float* __restrict__ fc1b,
                 const float* __restrict__ fc2W, const float* __restrict__ fc2b,
                 const float* __restrict__ outW, const float* __restrict__ outb,
                 float* __restrict__ out)
{
    __shared__ float l0[AF], l1[HF], rr[2], hs[2][AF];
    const int b = blockIdx.x, tid = threadIdx.x;
    const int col = tid & 63, half = tid >> 6;
    {
        const float sc = ss2[col], sh = ss2[AF + col];
        float s = 0.f;
        #pragma unroll 4
        for (int a = half * 16; a < half * 16 + 16; ++a) {
            const size_t o = (size_t)(b * 32 + a) * AF + col;
            s += fsp(x[o] + fmaf(summed[o], sc, sh));
        }
        hs[half][col] = s;
    }
    __syncthreads();
    if (tid < AF) l0[tid] = fsp((hs[0][tid] + hs[1][tid]) * (1.f / 32.f));
    __syncthreads();
    float acc = fc1b[tid];
    #pragma unroll 4
    for (int k = 0; k < AF; ++k) acc = fmaf(l0[k], fc1W[k * HF + tid], acc);
    l1[tid] = fsp(acc);
    __syncthreads();
    acc = fc2b[tid];
    #pragma unroll 4
    for (int k = 0; k < HF; ++k) acc = fmaf(l1[k], fc2W[k * HF + tid], acc);
    float v = fsp(acc) * outW[tid];
    #pragma unroll
    for (int off = 32; off > 0; off >>= 1) v += __shfl_down(v, off, 64);
    if ((tid & 63) == 0) rr[tid >> 6] = v;
    __syncthreads();
    if (tid == 0) out[b] = rr[0] + rr[1] + outb[0];
}

extern "C" void kernel_launch(void* const* d_in, const int* in_sizes, int n_in,
                              void* d_out, int out_size, void* d_ws, size_t ws_size,
                              hipStream_t stream)
{
    const float* atom_fea = (const float*)d_in[0];
    const float* nbr_fea  = (const float*)d_in[1];
    const int*   nbr_idx  = (const int*)d_in[2];
    const float* emb_W  = (const float*)d_in[4];
    const float* emb_b  = (const float*)d_in[5];
    const float* conv_W = (const float*)d_in[6];
    const float* conv_b = (const float*)d_in[7];
    const float* bn1_g  = (const float*)d_in[8];
    const float* bn1_b  = (const float*)d_in[9];
    const float* bn2_g  = (const float*)d_in[10];
    const float* bn2_b  = (const float*)d_in[11];
    const float* fc1W   = (const float*)d_in[12];
    const float* fc1b   = (const float*)d_in[13];
    const float* fc2W   = (const float*)d_in[14];
    const float* fc2b   = (const float*)d_in[15];
    const float* outW   = (const float*)d_in[16];
    const float* outb   = (const float*)d_in[17];
    float* out = (float*)d_out;
    float* ws  = (float*)d_ws;

    // workspace (~146 MB)
    float*    x_a    = ws;
    float*    x_b    = x_a + (size_t)NA * AF;
    float*    Sbuf   = x_b + (size_t)NA * AF;
    unsigned* Pb     = (unsigned*)(Sbuf + (size_t)NA * C2);   // NA x 64 uints (bf16 pairs)
    float*    summed = (float*)(Pb + (size_t)NA * 64);
    float*    P1s    = summed + (size_t)NA * AF;              // [1024][128]
    float*    P1q    = P1s + (size_t)GRID_CONV * C2;
    float*    P2s    = P1q + (size_t)GRID_CONV * C2;          // [2048][64]
    float*    P2q    = P2s + (size_t)GRID_APPLY * AF;
    float*    ss1    = P2q + (size_t)GRID_APPLY * AF;
    float*    ss2    = ss1 + 2 * C2;
    unsigned* gbuf   = (unsigned*)(ss2 + 2 * AF);             // NM x 64 uints (bf16 pairs)

    float* xcur = x_a;
    spx_kernel<true><<<NA / 16, 256, 0, stream>>>(nullptr, nullptr, nullptr,
                                                  atom_fea, emb_W, emb_b,
                                                  conv_W, conv_b, xcur, Sbuf, Pb);
    for (int l = 0; l < NCONV; ++l) {
        const float* W2 = conv_W + (size_t)l * (C2 + NBR) * C2 + (size_t)C2 * C2;
        conv8_kernel<<<GRID_CONV, 256, 0, stream>>>(nbr_fea, nbr_idx, W2,
                                                    Sbuf, Pb, P1s, P1q, gbuf);
        bn_finalize_plain<<<C2, 256, 0, stream>>>(P1s, P1q, GRID_CONV, C2, 1.f / (float)NM,
                                                  bn1_g + l * C2, bn1_b + l * C2, ss1);
        apply_g_kernel<<<GRID_APPLY, 256, 0, stream>>>(gbuf, ss1, summed, P2s, P2q);
        bn_finalize_plain<<<AF, 256, 0, stream>>>(P2s, P2q, GRID_APPLY, AF, 1.f / (float)NA,
                                                  bn2_g + l * AF, bn2_b + l * AF, ss2);
        if (l < NCONV - 1) {
            float* xnext = (xcur == x_a) ? x_b : x_a;
            spx_kernel<false><<<NA / 16, 256, 0, stream>>>(xcur, summed, ss2,
                                                           nullptr, nullptr, nullptr,
                                                           conv_W + (size_t)(l + 1) * (C2 + NBR) * C2,
                                                           conv_b + (size_t)(l + 1) * C2,
                                                           xnext, Sbuf, Pb);
            xcur = xnext;
        }
    }
    head_kernel<<<BB, 128, 0, stream>>>(xcur, summed, ss2,
                                        fc1W, fc1b, fc2W, fc2b, outW, outb, out);
}